// Round 1
// baseline (3192.088 us; speedup 1.0000x reference)
//
#include <hip/hip_runtime.h>
#include <math.h>

// ---------------------------------------------------------------------------
// AttentionFlow: fp32 implementation.
//  pass1: score(edges1, mem_emb) -> segment softmax by src node -> top-256/group
//         -> node_score out + pruned update of emb (emb1, in ws)
//  pass0: score(edges0, emb1) -> segment softmax -> update (agg0 = out1 region)
//         -> final leaky(emb2 @ Wlin + blin) written in-place to out1
// fp32 everywhere: top-k selection gap (~0.07 in logit space, sigma~23) rules
// out bf16 matmuls this round.
// ---------------------------------------------------------------------------

#define NNODES 100000
#define DDIM   256
#define NH     512
#define NGROUP 64
#define EPG    1024
#define E1N    65536
#define E0N    65536
#define KTOP   256
#define TE     32
#define KC     64

__device__ __forceinline__ float lrelu(float x) { return x > 0.0f ? x : 0.01f * x; }

// monotonic float<->uint mapping for atomicMax-based segment max
__device__ __forceinline__ unsigned fenc(float f) {
  unsigned u = __float_as_uint(f);
  return (u & 0x80000000u) ? ~u : (u | 0x80000000u);
}
__device__ __forceinline__ float fdec(unsigned k) {
  unsigned u = (k & 0x80000000u) ? (k & 0x7FFFFFFFu) : ~k;
  return __uint_as_float(u);
}

#define FMA8(ACC, EI, X, W0, W1)                                    \
  ACC[(EI)*8+0] += (X) * (W0).x; ACC[(EI)*8+1] += (X) * (W0).y;     \
  ACC[(EI)*8+2] += (X) * (W0).z; ACC[(EI)*8+3] += (X) * (W0).w;     \
  ACC[(EI)*8+4] += (X) * (W1).x; ACC[(EI)*8+5] += (X) * (W1).y;     \
  ACC[(EI)*8+6] += (X) * (W1).z; ACC[(EI)*8+7] += (X) * (W1).w;

// ---------------------------------------------------------------------------
// qterm[g][o] = b[o] + qs[g] @ W[512:768] + qr[g] @ W[768:1024]  (for Wl & Wr)
// ---------------------------------------------------------------------------
__global__ __launch_bounds__(512)
void qterm_kernel(const float* __restrict__ qse, const float* __restrict__ qre,
                  const float* __restrict__ Wl, const float* __restrict__ bl,
                  const float* __restrict__ Wr, const float* __restrict__ br,
                  float* __restrict__ qtl, float* __restrict__ qtr)
{
  const int g = blockIdx.x;
  const int o = threadIdx.x;  // 0..511
  __shared__ float sq[DDIM];
  __shared__ float sr[DDIM];
  if (o < DDIM) sq[o] = qse[(size_t)g * DDIM + o];
  else          sr[o - DDIM] = qre[(size_t)g * DDIM + (o - DDIM)];
  __syncthreads();
  float al = bl[o], ar = br[o];
  for (int k = 0; k < DDIM; ++k) {
    float a = sq[k], b = sr[k];
    al += a * Wl[(size_t)(512 + k) * NH + o] + b * Wl[(size_t)(768 + k) * NH + o];
    ar += a * Wr[(size_t)(512 + k) * NH + o] + b * Wr[(size_t)(768 + k) * NH + o];
  }
  qtl[(size_t)g * NH + o] = al;
  qtr[(size_t)g * NH + o] = ar;
}

// ---------------------------------------------------------------------------
// score kernel: 32 edges/block, 256 threads. Thread tile: 8 edges x 8 outs.
//  ob = (tid&63)*8 (output block), eb = (tid>>6)*8 (edge block).
// ---------------------------------------------------------------------------
template<int METACOL>
__device__ __forceinline__ void gemm512(float acc[64], const float* __restrict__ W,
                                        const float* __restrict__ emb,
                                        const float* __restrict__ rel,
                                        float xs[TE][KC + 4], int meta[TE][3],
                                        int e0, int le, int ls, int eb, int ob)
{
  for (int c = 0; c < 8; ++c) {
    __syncthreads();
    {
      const float* src;
      if (c < 4) src = emb + (size_t)meta[le][METACOL] * DDIM + c * KC;
      else       src = rel + (size_t)(e0 + le) * DDIM + (c - 4) * KC;
      float4 a = *(const float4*)(src + ls * 8);
      float4 b = *(const float4*)(src + ls * 8 + 4);
      *(float4*)&xs[le][ls * 8]     = a;
      *(float4*)&xs[le][ls * 8 + 4] = b;
    }
    __syncthreads();
    const float* wb = W + (size_t)(c * KC) * NH + ob;
#pragma unroll 2
    for (int k = 0; k < KC; ++k) {
      float4 w0 = *(const float4*)(wb + (size_t)k * NH);
      float4 w1 = *(const float4*)(wb + (size_t)k * NH + 4);
#pragma unroll
      for (int ei = 0; ei < 8; ++ei) {
        float x = xs[eb + ei][k];
        FMA8(acc, ei, x, w0, w1)
      }
    }
  }
}

__global__ __launch_bounds__(256, 2)
void score_kernel(const int* __restrict__ edges,
                  const float* __restrict__ emb,
                  const float* __restrict__ rel,
                  const float* __restrict__ Wl,
                  const float* __restrict__ Wr,
                  const float* __restrict__ Wc,
                  const float* __restrict__ bc,
                  const float* __restrict__ qtl,
                  const float* __restrict__ qtr,
                  float* __restrict__ logits)
{
  __shared__ float xs[TE][KC + 4];     // gathered input chunk (e-major, padded)
  __shared__ float rh[TE][DDIM + 4];   // half of leaky(r_pre)
  __shared__ int   meta[TE][3];        // i, j, group

  const int tid = threadIdx.x;
  const int e0  = blockIdx.x * TE;
  const int ob  = (tid & 63) * 8;
  const int eb  = (tid >> 6) * 8;
  const int le  = tid >> 3;
  const int ls  = tid & 7;

  if (tid < TE) {
    const int* er = edges + (size_t)(e0 + tid) * 8;
    meta[tid][0] = er[6];
    meta[tid][1] = er[7];
    meta[tid][2] = er[0];
  }

  // ---------------- R phase: r_pre = [emb_j | rel] @ Wr[0:512] ----------------
  float accR[64];
#pragma unroll
  for (int q = 0; q < 64; ++q) accR[q] = 0.0f;
  gemm512<1>(accR, Wr, emb, rel, xs, meta, e0, le, ls, eb, ob);

#pragma unroll
  for (int ei = 0; ei < 8; ++ei) {
    int g = meta[eb + ei][2];
    const float* q = qtr + (size_t)g * NH + ob;
    float4 q0 = *(const float4*)q;
    float4 q1 = *(const float4*)(q + 4);
    float qq[8] = {q0.x, q0.y, q0.z, q0.w, q1.x, q1.y, q1.z, q1.w};
#pragma unroll
    for (int oi = 0; oi < 8; ++oi)
      accR[ei * 8 + oi] = lrelu(accR[ei * 8 + oi] + qq[oi]);
  }

  // ---------------- C phase: r_out = leaky_r @ Wc + bc (two halves) -----------
  float accC[64];
  {
    float4 b0 = *(const float4*)(bc + ob);
    float4 b1 = *(const float4*)(bc + ob + 4);
    float bb2[8] = {b0.x, b0.y, b0.z, b0.w, b1.x, b1.y, b1.z, b1.w};
#pragma unroll
    for (int ei = 0; ei < 8; ++ei)
#pragma unroll
      for (int oi = 0; oi < 8; ++oi) accC[ei * 8 + oi] = bb2[oi];
  }

  for (int half = 0; half < 2; ++half) {
    __syncthreads();
    if ((ob < DDIM) == (half == 0)) {
      int oo = ob - half * DDIM;
#pragma unroll
      for (int ei = 0; ei < 8; ++ei) {
        float4 v0 = make_float4(accR[ei*8+0], accR[ei*8+1], accR[ei*8+2], accR[ei*8+3]);
        float4 v1 = make_float4(accR[ei*8+4], accR[ei*8+5], accR[ei*8+6], accR[ei*8+7]);
        *(float4*)&rh[eb + ei][oo]     = v0;
        *(float4*)&rh[eb + ei][oo + 4] = v1;
      }
    }
    __syncthreads();
    const float* wb = Wc + (size_t)(half * DDIM) * NH + ob;
#pragma unroll 2
    for (int k = 0; k < DDIM; ++k) {
      float4 w0 = *(const float4*)(wb + (size_t)k * NH);
      float4 w1 = *(const float4*)(wb + (size_t)k * NH + 4);
#pragma unroll
      for (int ei = 0; ei < 8; ++ei) {
        float x = rh[eb + ei][k];
        FMA8(accC, ei, x, w0, w1)
      }
    }
  }

  // ---------------- L phase: l = leaky([emb_i | rel] @ Wl[0:512] + qtl) -------
  float accL[64];
#pragma unroll
  for (int q = 0; q < 64; ++q) accL[q] = 0.0f;
  gemm512<0>(accL, Wl, emb, rel, xs, meta, e0, le, ls, eb, ob);

#pragma unroll
  for (int ei = 0; ei < 8; ++ei) {
    int g = meta[eb + ei][2];
    const float* q = qtl + (size_t)g * NH + ob;
    float4 q0 = *(const float4*)q;
    float4 q1 = *(const float4*)(q + 4);
    float qq[8] = {q0.x, q0.y, q0.z, q0.w, q1.x, q1.y, q1.z, q1.w};
#pragma unroll
    for (int oi = 0; oi < 8; ++oi)
      accL[ei * 8 + oi] = lrelu(accL[ei * 8 + oi] + qq[oi]);
  }

  // ---------------- dot(l, r_out), reduce across wave -------------------------
  float p[8];
#pragma unroll
  for (int ei = 0; ei < 8; ++ei) {
    float s = 0.0f;
#pragma unroll
    for (int oi = 0; oi < 8; ++oi) s += accL[ei * 8 + oi] * accC[ei * 8 + oi];
    p[ei] = s;
  }
#pragma unroll
  for (int off = 1; off < 64; off <<= 1) {
#pragma unroll
    for (int ei = 0; ei < 8; ++ei) p[ei] += __shfl_xor(p[ei], off);
  }
  const int lane = tid & 63;
#pragma unroll
  for (int ei = 0; ei < 8; ++ei)
    if (lane == ei) logits[e0 + eb + ei] = p[ei];
}

// ---------------------------------------------------------------------------
// segment softmax over source node (col 6) via atomics
// ---------------------------------------------------------------------------
__global__ void smax_max_kernel(const int* __restrict__ edges, const float* __restrict__ logits,
                                unsigned* __restrict__ mkey, int E)
{
  int e = blockIdx.x * blockDim.x + threadIdx.x;
  if (e < E) atomicMax(mkey + edges[(size_t)e * 8 + 6], fenc(logits[e]));
}

__global__ void smax_exp_kernel(const int* __restrict__ edges, const float* __restrict__ logits,
                                const unsigned* __restrict__ mkey, float* __restrict__ ssum,
                                float* __restrict__ sm, int E)
{
  int e = blockIdx.x * blockDim.x + threadIdx.x;
  if (e < E) {
    int s = edges[(size_t)e * 8 + 6];
    float ev = expf(logits[e] - fdec(mkey[s]));
    sm[e] = ev;
    atomicAdd(ssum + s, ev);
  }
}

__global__ void smax_norm_kernel(const int* __restrict__ edges, const float* __restrict__ ssum,
                                 float* __restrict__ sm, const float* __restrict__ nscore,
                                 float* __restrict__ ta, int E)
{
  int e = blockIdx.x * blockDim.x + threadIdx.x;
  if (e < E) {
    int s = edges[(size_t)e * 8 + 6];
    float v = sm[e] / ssum[s];
    sm[e] = v;
    if (ta) ta[e] = v * nscore[s];
  }
}

// ---------------------------------------------------------------------------
// per-group top-256 of 1024 (jax.lax.top_k order: desc value, ties -> low idx)
// bitonic sort of 1024 (val, idx) pairs; 1 block per group
// ---------------------------------------------------------------------------
__global__ __launch_bounds__(256)
void topk_kernel(const float* __restrict__ ta, const float* __restrict__ sm1,
                 const int* __restrict__ edges1,
                 float* __restrict__ out0, float* __restrict__ out2,
                 float* __restrict__ out3, float* __restrict__ smp,
                 int* __restrict__ prn_i, int* __restrict__ prn_j,
                 int* __restrict__ cnt1)
{
  __shared__ float v[EPG];
  __shared__ int   ix[EPG];
  const int g = blockIdx.x, tid = threadIdx.x;
  for (int t = tid; t < EPG; t += 256) { v[t] = ta[(size_t)g * EPG + t]; ix[t] = t; }
  __syncthreads();
  for (int k = 2; k <= EPG; k <<= 1) {
    for (int j = k >> 1; j > 0; j >>= 1) {
      for (int t = tid; t < EPG; t += 256) {
        int l = t ^ j;
        if (l > t) {
          float va = v[t], vb = v[l];
          int ia = ix[t], ib = ix[l];
          // aFirst: t-elem precedes l-elem in final (desc, idx-stable) order
          bool aFirst = (va > vb) || (va == vb && ia < ib);
          bool up = ((t & k) == 0);
          bool sw = up ? !aFirst : aFirst;
          if (sw) { v[t] = vb; ix[t] = ib; v[l] = va; ix[l] = ia; }
        }
      }
      __syncthreads();
    }
  }
  // first 256 entries are the top-k in order
  const int r = tid;
  const int oi = ix[r];
  const float val = v[r];                 // pruned target_att
  const int orig = g * EPG + oi;
  out3[(size_t)g * KTOP + r] = (float)orig;
  const int* er = edges1 + (size_t)orig * 8;
#pragma unroll
  for (int c = 0; c < 8; ++c)
    out2[((size_t)(g * KTOP + r)) * 8 + c] = (float)er[c];
  const int ii = er[6], jj = er[7];
  const float smv = sm1[orig];
  smp[(size_t)g * KTOP + r] = smv;
  prn_i[(size_t)g * KTOP + r] = ii;
  prn_j[(size_t)g * KTOP + r] = jj;
  atomicAdd(out0 + jj, smv * val);
  atomicAdd(cnt1 + jj, 1);
}

// ---------------------------------------------------------------------------
// agg[j] += w[e] * src_emb[i]   (one block per edge, 256 threads = 256 dims)
// ---------------------------------------------------------------------------
__global__ void scatter_kernel(const int* __restrict__ idx_i, int si,
                               const int* __restrict__ idx_j, int sj,
                               const float* __restrict__ w,
                               const float* __restrict__ semb,
                               float* __restrict__ agg)
{
  const int e = blockIdx.x;
  const int o = threadIdx.x;
  const int i = idx_i[(size_t)e * si];
  const int j = idx_j[(size_t)e * sj];
  atomicAdd(agg + (size_t)j * DDIM + o, w[e] * semb[(size_t)i * DDIM + o]);
}

__global__ void cnt_kernel(const int* __restrict__ idx_j, int sj, int* __restrict__ cnt, int E)
{
  int e = blockIdx.x * blockDim.x + threadIdx.x;
  if (e < E) atomicAdd(cnt + idx_j[(size_t)e * sj], 1);
}

// emb1 := (cnt>0) ? agg : mem_emb   (agg updated in place; grid = NNODES blocks)
__global__ void combine_kernel(const float* __restrict__ mememb, const int* __restrict__ cnt,
                               float* __restrict__ agg)
{
  size_t id = (size_t)blockIdx.x * 256 + threadIdx.x;
  if (cnt[id >> 8] == 0) agg[id] = mememb[id];
}

// ---------------------------------------------------------------------------
// final: out[r] = leaky( (cnt0[r]>0 ? agg0[r] : emb1[r]) @ Wlin + blin )
// in-place on out1 (each block fully reads its 64 rows before writing them)
// ---------------------------------------------------------------------------
__global__ __launch_bounds__(256, 2)
void final_kernel(const float* __restrict__ emb1, const float* __restrict__ agg0,
                  const int* __restrict__ cnt0, const float* __restrict__ Wlin,
                  const float* __restrict__ blin, float* __restrict__ out)
{
  __shared__ float As[64][68];
  __shared__ int scnt[64];
  const int tid = threadIdx.x;
  const int r0 = blockIdx.x * 64;
  const int ob = (tid & 31) * 8;
  const int rb = (tid >> 5) * 8;
  if (tid < 64) {
    int r = r0 + tid;
    scnt[tid] = (r < NNODES) ? cnt0[r] : 0;
  }
  float acc[64];
  {
    float4 b0 = *(const float4*)(blin + ob);
    float4 b1 = *(const float4*)(blin + ob + 4);
    float bb2[8] = {b0.x, b0.y, b0.z, b0.w, b1.x, b1.y, b1.z, b1.w};
#pragma unroll
    for (int ri = 0; ri < 8; ++ri)
#pragma unroll
      for (int oi = 0; oi < 8; ++oi) acc[ri * 8 + oi] = bb2[oi];
  }
  const int le = tid >> 2, ls = tid & 3;
  for (int c = 0; c < 4; ++c) {
    __syncthreads();
    {
      int r = r0 + le;
      int rc = (r < NNODES) ? r : 0;
      const float* base = (scnt[le] > 0) ? agg0 : emb1;
      const float4* s4 = (const float4*)(base + (size_t)rc * DDIM + c * 64 + ls * 16);
      float4 a0 = s4[0], a1 = s4[1], a2 = s4[2], a3 = s4[3];
      *(float4*)&As[le][ls * 16]      = a0;
      *(float4*)&As[le][ls * 16 + 4]  = a1;
      *(float4*)&As[le][ls * 16 + 8]  = a2;
      *(float4*)&As[le][ls * 16 + 12] = a3;
    }
    __syncthreads();
    const float* wb = Wlin + (size_t)(c * 64) * DDIM + ob;
#pragma unroll 2
    for (int k = 0; k < 64; ++k) {
      float4 w0 = *(const float4*)(wb + (size_t)k * DDIM);
      float4 w1 = *(const float4*)(wb + (size_t)k * DDIM + 4);
#pragma unroll
      for (int ri = 0; ri < 8; ++ri) {
        float x = As[rb + ri][k];
        FMA8(acc, ri, x, w0, w1)
      }
    }
  }
#pragma unroll
  for (int ri = 0; ri < 8; ++ri) {
    int r = r0 + rb + ri;
    if (r < NNODES) {
      float4 o0 = make_float4(lrelu(acc[ri*8+0]), lrelu(acc[ri*8+1]),
                              lrelu(acc[ri*8+2]), lrelu(acc[ri*8+3]));
      float4 o1 = make_float4(lrelu(acc[ri*8+4]), lrelu(acc[ri*8+5]),
                              lrelu(acc[ri*8+6]), lrelu(acc[ri*8+7]));
      *(float4*)(out + (size_t)r * DDIM + ob)     = o0;
      *(float4*)(out + (size_t)r * DDIM + ob + 4) = o1;
    }
  }
}

// ---------------------------------------------------------------------------
extern "C" void kernel_launch(void* const* d_in, const int* in_sizes, int n_in,
                              void* d_out, int out_size, void* d_ws, size_t ws_size,
                              hipStream_t stream)
{
  (void)in_sizes; (void)n_in; (void)out_size; (void)ws_size;

  const float* node_score = (const float*)d_in[1];
  const int*   edges0 = (const int*)d_in[2];
  const int*   edges1 = (const int*)d_in[3];
  const float* rel0   = (const float*)d_in[4];
  const float* rel1   = (const float*)d_in[5];
  const float* mememb = (const float*)d_in[6];
  const float* qse    = (const float*)d_in[7];
  const float* qre    = (const float*)d_in[8];
  const float* Wl     = (const float*)d_in[9];
  const float* bl     = (const float*)d_in[10];
  const float* Wr     = (const float*)d_in[11];
  const float* br     = (const float*)d_in[12];
  const float* Wc     = (const float*)d_in[13];
  const float* bc     = (const float*)d_in[14];
  const float* Wlin   = (const float*)d_in[15];
  const float* blin   = (const float*)d_in[16];

  float* out0 = (float*)d_out;                       // updated_node_score [100000]
  float* out1 = out0 + NNODES;                       // emb [100000*256]
  float* out2 = out1 + (size_t)NNODES * DDIM;        // pruned_edges [16384*8] (as float)
  float* out3 = out2 + (size_t)NGROUP * KTOP * 8;    // orig_indices [16384] (as float)

  char* wptr = (char*)d_ws;
  auto alloc = [&](size_t bytes) -> char* {
    char* p = wptr;
    wptr += (bytes + 255) & ~(size_t)255;
    return p;
  };
  float*    qtl     = (float*)alloc((size_t)NGROUP * NH * 4);
  float*    qtr     = (float*)alloc((size_t)NGROUP * NH * 4);
  float*    logits1 = (float*)alloc((size_t)E1N * 4);
  float*    sm1     = (float*)alloc((size_t)E1N * 4);
  float*    ta      = (float*)alloc((size_t)E1N * 4);
  float*    logits0 = (float*)alloc((size_t)E0N * 4);
  float*    sm0     = (float*)alloc((size_t)E0N * 4);
  unsigned* mkey    = (unsigned*)alloc((size_t)NNODES * 4);
  float*    ssum    = (float*)alloc((size_t)NNODES * 4);
  int*      cnt1    = (int*)alloc((size_t)NNODES * 4);
  int*      cnt0    = (int*)alloc((size_t)NNODES * 4);
  float*    smp     = (float*)alloc((size_t)NGROUP * KTOP * 4);
  int*      prn_i   = (int*)alloc((size_t)NGROUP * KTOP * 4);
  int*      prn_j   = (int*)alloc((size_t)NGROUP * KTOP * 4);
  float*    agg1    = (float*)alloc((size_t)NNODES * DDIM * 4);   // emb1

  // ---- pass 1 init ----
  hipMemsetAsync(agg1, 0, (size_t)NNODES * DDIM * 4, stream);
  hipMemsetAsync(cnt1, 0, (size_t)NNODES * 4, stream);
  hipMemsetAsync(mkey, 0, (size_t)NNODES * 4, stream);
  hipMemsetAsync(ssum, 0, (size_t)NNODES * 4, stream);
  hipMemsetAsync(out0, 0, (size_t)NNODES * 4, stream);

  qterm_kernel<<<NGROUP, 512, 0, stream>>>(qse, qre, Wl, bl, Wr, br, qtl, qtr);
  score_kernel<<<E1N / TE, 256, 0, stream>>>(edges1, mememb, rel1, Wl, Wr, Wc, bc,
                                             qtl, qtr, logits1);
  smax_max_kernel<<<E1N / 256, 256, 0, stream>>>(edges1, logits1, mkey, E1N);
  smax_exp_kernel<<<E1N / 256, 256, 0, stream>>>(edges1, logits1, mkey, ssum, sm1, E1N);
  smax_norm_kernel<<<E1N / 256, 256, 0, stream>>>(edges1, ssum, sm1, node_score, ta, E1N);
  topk_kernel<<<NGROUP, 256, 0, stream>>>(ta, sm1, edges1, out0, out2, out3,
                                          smp, prn_i, prn_j, cnt1);
  scatter_kernel<<<NGROUP * KTOP, 256, 0, stream>>>(prn_i, 1, prn_j, 1, smp, mememb, agg1);
  combine_kernel<<<NNODES, 256, 0, stream>>>(mememb, cnt1, agg1);   // agg1 -> emb1

  // ---- pass 0 init ----
  hipMemsetAsync(mkey, 0, (size_t)NNODES * 4, stream);
  hipMemsetAsync(ssum, 0, (size_t)NNODES * 4, stream);
  hipMemsetAsync(cnt0, 0, (size_t)NNODES * 4, stream);
  hipMemsetAsync(out1, 0, (size_t)NNODES * DDIM * 4, stream);       // agg0

  score_kernel<<<E0N / TE, 256, 0, stream>>>(edges0, agg1, rel0, Wl, Wr, Wc, bc,
                                             qtl, qtr, logits0);
  smax_max_kernel<<<E0N / 256, 256, 0, stream>>>(edges0, logits0, mkey, E0N);
  smax_exp_kernel<<<E0N / 256, 256, 0, stream>>>(edges0, logits0, mkey, ssum, sm0, E0N);
  smax_norm_kernel<<<E0N / 256, 256, 0, stream>>>(edges0, ssum, sm0, nullptr, nullptr, E0N);
  scatter_kernel<<<E0N, 256, 0, stream>>>(edges0 + 6, 8, edges0 + 7, 8, sm0, agg1, out1);
  cnt_kernel<<<E0N / 256, 256, 0, stream>>>(edges0 + 7, 8, cnt0, E0N);
  final_kernel<<<(NNODES + 63) / 64, 256, 0, stream>>>(agg1, out1, cnt0, Wlin, blin, out1);
}